// Round 10
// baseline (351.338 us; speedup 1.0000x reference)
//
#include <hip/hip_runtime.h>
#include <math.h>

// Problem constants
#define B_DIM 8
#define T_DIM 4096
#define K_DIM 1024   // IN_DIM
#define H_DIM 1024   // HIDDEN
#define M_DIM (B_DIM * T_DIM)   // 32768 rows

#define CH 64               // scan chunk length
#define NC (T_DIM / CH)     // 64 chunks per channel
#define BK 32               // GEMM K-step (dense 1KB frag reads, no swizzle)
#define NKS (K_DIM / BK)    // 32 K-steps

typedef short bf16x8 __attribute__((ext_vector_type(8)));   // 8 bf16 = 4 VGPRs
typedef float f32x4  __attribute__((ext_vector_type(4)));

// ---------- helpers ----------
__device__ __forceinline__ unsigned short f2bf(float f) {
  unsigned int u = __builtin_bit_cast(unsigned int, f);
  u += 0x7FFFu + ((u >> 16) & 1u);   // round-to-nearest-even
  return (unsigned short)(u >> 16);
}

__device__ __forceinline__ void gload_lds16(const void* g, void* l) {
  __builtin_amdgcn_global_load_lds(
      (const __attribute__((address_space(1))) unsigned int*)g,
      (__attribute__((address_space(3))) unsigned int*)l,
      16 /*bytes, literal*/, 0 /*offset*/, 0 /*aux*/);
}

// fast softplus: v_exp_f32 + v_log_f32
__device__ __forceinline__ float softplus_fast(float x) {
  float e = __expf(-fabsf(x));
  return fmaxf(x, 0.f) + __logf(1.f + e);
}

// fast tanh: 1 - 2/(e^{2x}+1). e=inf -> 1, e=0 -> -1 (correct saturation).
__device__ __forceinline__ float tanh_fast(float x) {
  float e = __expf(2.f * x);
  return 1.f - 2.f * __builtin_amdgcn_rcpf(e + 1.f);
}

// ---------- f32 -> bf16 convert (8 elems/thread) ----------
__global__ __launch_bounds__(256) void k_cvt(const float* __restrict__ in,
                                             unsigned short* __restrict__ out,
                                             int n8) {
  int i = blockIdx.x * 256 + threadIdx.x;
  if (i >= n8) return;
  float4 v0 = ((const float4*)in)[i * 2 + 0];
  float4 v1 = ((const float4*)in)[i * 2 + 1];
  bf16x8 r;
  r[0] = (short)f2bf(v0.x); r[1] = (short)f2bf(v0.y);
  r[2] = (short)f2bf(v0.z); r[3] = (short)f2bf(v0.w);
  r[4] = (short)f2bf(v1.x); r[5] = (short)f2bf(v1.y);
  r[6] = (short)f2bf(v1.z); r[7] = (short)f2bf(v1.w);
  ((bf16x8*)out)[i] = r;
}

// ---------- dual GEMM: 4-buffer pipeline, counted vmcnt, aging = 2 tiles --
// BM=256 X-rows, 128 real h-cols (virtual B 256 rows: vrow[0:16)=Wd[0:16),
// [16:32)=Wb[0:16), [32:48)=Wd[16:32), ... — R5-verified mapping). 8 waves
// (2M x 4Nq), wave = 128 rows x 64 vcols; BK=32 = one MFMA-K => frag read is
// a DENSE 1KB per wave (fr=row, hi=16B chunk): bank-perfect, no swizzle.
// Pipeline: 4 LDS buffers; iter t: vmcnt(4) [tile t's 4 loads landed; t+1's
// still flying], barrier, stage(t+2) [4 gloads], compute(t) [12 ds_read +
// 32 MFMA]. Loads age TWO full iterations (~800+ cyc) before their drain.
__global__ __launch_bounds__(512, 1) void k_gemm_dual(
    const unsigned short* __restrict__ Xb,    // [M][K] bf16 bits
    const unsigned short* __restrict__ Wdb,   // [H][K] bf16 bits
    const unsigned short* __restrict__ Wbb,   // [H][K] bf16 bits
    const float* __restrict__ bd,
    const float* __restrict__ bb,
    const float* __restrict__ A_log,
    float* __restrict__ a_out,                // [M][H]
    float* __restrict__ b_out,                // [M][H] (aliases d_out)
    float* __restrict__ aggA,                 // [B*NC][H]
    float* __restrict__ aggB)                 // [B*NC][H]
{
  __shared__ unsigned short As[4][256 * BK];   // 4 x 16 KiB = 64 KiB
  __shared__ unsigned short Bs[4][256 * BK];   // 4 x 16 KiB = 64 KiB

  const int tid  = threadIdx.x;
  // XCD-grouped mapping: 1024 blocks = 8 XCD x 128; n-tile fastest.
  const int wgid = blockIdx.x;
  const int xcd  = wgid & 7;
  const int j    = wgid >> 3;                 // 0..127 per XCD
  const int bm   = (xcd * 16 + (j >> 3)) * 256;   // m-tile (256 rows)
  const int bn   = (j & 7) * 128;                 // h-col base (128 cols)

  const int w    = tid >> 6;
  const int lane = tid & 63;
  const int wm   = (w >> 2) * 128;   // 2 wave-rows of 128
  const int wq   = w & 3;            // 4 wave-col-quarters
  const int wn   = wq * 64;          // virtual col base

  f32x4 acc[8][4];
  const f32x4 z4 = {0.f, 0.f, 0.f, 0.f};
#pragma unroll
  for (int m = 0; m < 8; m++)
#pragma unroll
    for (int n = 0; n < 4; n++) acc[m][n] = z4;

  const int fr = lane & 15;
  const int hi = lane >> 4;

  // ---- staging invariants: LINEAR both sides (no swizzle needed at BK=32)
  // 1024 16B-chunks per matrix per tile; 2 A + 2 B chunks per thread.
  const unsigned short* gA[2];
  const unsigned short* gB[2];
  int ldsoff[2];
#pragma unroll
  for (int jj = 0; jj < 2; jj++) {
    int idx = jj * 512 + tid;        // 0..1023
    int row = idx >> 2;              // 0..255
    int ch  = idx & 3;               // 16B chunk within 64B row
    ldsoff[jj] = idx * 16;
    gA[jj] = Xb + (((size_t)(bm + row)) << 10) + (size_t)(ch * 8);
    int h = bn + (row >> 6) * 32 + (row & 31);   // virtual row -> h col
    const unsigned short* Wsrc = (row & 32) ? Wbb : Wdb;
    gB[jj] = Wsrc + (((size_t)h) << 10) + (size_t)(ch * 8);
  }

#define STAGE(T, D)                                                           \
  do {                                                                        \
    _Pragma("unroll")                                                         \
    for (int jj = 0; jj < 2; jj++) {                                          \
      gload_lds16(gA[jj] + (T) * BK, (char*)As[D] + ldsoff[jj]);              \
      gload_lds16(gB[jj] + (T) * BK, (char*)Bs[D] + ldsoff[jj]);              \
    }                                                                         \
  } while (0)

  // ---- ds_read bases: frag addr = (rowbase + fr)*64 + hi*16 (+ immediates)
  const char* bA = (const char*)As + ((wm + fr) * 64 + hi * 16);
  const char* bB = (const char*)Bs + ((wn + fr) * 64 + hi * 16);

// one pipelined iteration; D = T&3 must be compile-time at each call site
#define BODY(T, D)                                                            \
  do {                                                                        \
    if ((T) + 2 < NKS) asm volatile("s_waitcnt vmcnt(4)" ::: "memory");       \
    else               asm volatile("s_waitcnt vmcnt(0)" ::: "memory");       \
    __builtin_amdgcn_s_barrier();                                             \
    if ((T) + 2 < NKS) STAGE((T) + 2, ((D) + 2) & 3);                         \
    bf16x8 Af[8], Bf[4];                                                      \
    _Pragma("unroll")                                                         \
    for (int m = 0; m < 8; m++)                                               \
      Af[m] = *(const bf16x8*)(bA + (D) * 16384 + m * 1024);                  \
    _Pragma("unroll")                                                         \
    for (int n = 0; n < 4; n++)                                               \
      Bf[n] = *(const bf16x8*)(bB + (D) * 16384 + n * 1024);                  \
    __builtin_amdgcn_s_setprio(1);                                            \
    _Pragma("unroll")                                                         \
    for (int m = 0; m < 8; m++)                                               \
      _Pragma("unroll")                                                       \
      for (int n = 0; n < 4; n++)                                             \
        acc[m][n] = __builtin_amdgcn_mfma_f32_16x16x32_bf16(                  \
            Af[m], Bf[n], acc[m][n], 0, 0, 0);                                \
    __builtin_amdgcn_s_setprio(0);                                            \
  } while (0)

  // prologue: fill buffers 0,1 (8 loads outstanding)
  STAGE(0, 0);
  STAGE(1, 1);

#pragma unroll 1
  for (int tb = 0; tb < NKS; tb += 4) {
    BODY(tb + 0, 0);
    BODY(tb + 1, 1);
    BODY(tb + 2, 2);
    BODY(tb + 3, 3);
  }

  // epilogue: C/D layout col = lane&15, row = (lane>>4)*4 + r  [m89-verified]
  // acc[m][np] = z1, acc[m][np+2] = z2, same h-col gn (R5-verified pairing).
  const int col   = fr;
  const int rbase = hi * 4;
  const int bidx  = bm >> 12;                            // batch (T=4096)
  const int cch0  = ((bm + wm) & (T_DIM - 1)) >> 6;      // first chunk id

#pragma unroll
  for (int np = 0; np < 2; np++) {
    int gn = bn + wq * 32 + np * 16 + col;
    float bdv = bd[gn];
    float bbv = bb[gn];
    float Ah  = __expf(A_log[gn]);
    float segA[8], segB[8];
#pragma unroll
    for (int m = 0; m < 8; m++) {
      float sA = 1.f, sB = 0.f;
#pragma unroll
      for (int r = 0; r < 4; r++) {
        int gm = bm + wm + m * 16 + rbase + r;
        float z1  = acc[m][np][r] + bdv;
        float z2  = acc[m][np + 2][r] + bbv;
        float dlt = softplus_fast(z1);
        float av  = __expf(-dlt * Ah);
        float bv  = dlt * z2;
        size_t off = (size_t)gm * H_DIM + (size_t)gn;
        a_out[off] = av;
        b_out[off] = bv;
        sB = fmaf(av, sB, bv);     // compose ascending t within 4-row run
        sA *= av;
      }
      segA[m] = sA; segB[m] = sB;
    }
    // ordered cross-lane compose per 64-row chunk group (m 0..3 / 4..7)
#pragma unroll
    for (int g = 0; g < 2; g++) {
      float chA = 1.f, chB = 0.f;
#pragma unroll
      for (int mi = 0; mi < 4; mi++) {
        int m = g * 4 + mi;
#pragma unroll
        for (int h2 = 0; h2 < 4; h2++) {
          float sa = __shfl(segA[m], col + h2 * 16, 64);
          float sb = __shfl(segB[m], col + h2 * 16, 64);
          chB = fmaf(sa, chB, sb);
          chA *= sa;
        }
      }
      if (lane < 16) {
        size_t o = ((size_t)(bidx * NC + cch0 + g) << 10) + (size_t)gn;
        aggA[o] = chA;
        aggB[o] = chB;
      }
    }
  }
#undef BODY
#undef STAGE
}

// ---------- scan pass 2: sequential scan over chunk aggregates ----------
__global__ __launch_bounds__(256) void k_scan_chunks(
    const float* __restrict__ aggA, const float* __restrict__ aggB,
    const float* __restrict__ h0, float* __restrict__ hstart)
{
  int idx = blockIdx.x * 256 + threadIdx.x;   // b*H + h
  int h   = idx & (H_DIM - 1);
  int b   = idx >> 10;
  float hc = h0[idx];
  for (int c = 0; c < NC; c++) {
    size_t o = ((size_t)(b * NC + c) << 10) + (size_t)h;
    hstart[o] = hc;
    hc = fmaf(aggA[o], hc, aggB[o]);
  }
}

// ---------- scan pass 3: re-apply within chunk + tanh ----------
__global__ __launch_bounds__(256) void k_scan_apply(
    const float* __restrict__ a_arr, const float* b_arr,
    const float* __restrict__ hstart, float* out)   // b_arr aliases out!
{
  int idx = blockIdx.x * 256 + threadIdx.x;
  int h   = idx & (H_DIM - 1);
  int bc  = idx >> 10;
  int c   = bc & (NC - 1);
  int b   = bc >> 6;
  size_t base = ((size_t)b * T_DIM + (size_t)c * CH) * H_DIM + (size_t)h;
  float hc = hstart[idx];
#pragma unroll 4
  for (int i = 0; i < CH; i++) {
    size_t o = base + (size_t)i * H_DIM;
    float at = a_arr[o];
    float bt = b_arr[o];       // read BEFORE the aliased write below
    hc = fmaf(at, hc, bt);
    out[o] = tanh_fast(hc);
  }
}

// ---------- launch ----------
extern "C" void kernel_launch(void* const* d_in, const int* in_sizes, int n_in,
                              void* d_out, int out_size, void* d_ws, size_t ws_size,
                              hipStream_t stream) {
  const float* x     = (const float*)d_in[0];
  const float* h0    = (const float*)d_in[1];
  const float* Wd    = (const float*)d_in[2];
  const float* bd    = (const float*)d_in[3];
  const float* Wb    = (const float*)d_in[4];
  const float* bb    = (const float*)d_in[5];
  const float* A_log = (const float*)d_in[6];
  float* out = (float*)d_out;

  char* ws = (char*)d_ws;
  unsigned short* xb   = (unsigned short*)(ws + 0);           //  64 MiB
  unsigned short* wdb  = (unsigned short*)(ws + 67108864);    //   2 MiB
  unsigned short* wbb  = (unsigned short*)(ws + 69206016);    //   2 MiB
  float*          aarr = (float*)(ws + 71303168);             // 128 MiB
  float*          aggA = (float*)(ws + 205520896);            //   2 MiB
  float*          aggB = (float*)(ws + 207618048);            //   2 MiB
  float*          hst  = (float*)(ws + 209715200);            //   2 MiB
  float*          barr = out;  // b_t staged in d_out, overwritten by k_scan_apply

  // converts
  k_cvt<<<(M_DIM * K_DIM / 8) / 256, 256, 0, stream>>>(x, xb, M_DIM * K_DIM / 8);
  k_cvt<<<(H_DIM * K_DIM / 8) / 256, 256, 0, stream>>>(Wd, wdb, H_DIM * K_DIM / 8);
  k_cvt<<<(H_DIM * K_DIM / 8) / 256, 256, 0, stream>>>(Wb, wbb, H_DIM * K_DIM / 8);

  // fused dual GEMM + nonlinearity + chunk-aggregate epilogue
  k_gemm_dual<<<(M_DIM / 256) * (H_DIM / 128), 512, 0, stream>>>(
      xb, wdb, wbb, bd, bb, A_log, aarr, barr, aggA, aggB);

  // chunked affine scan over T (agg pass fused into GEMM)
  k_scan_chunks<<<(B_DIM * H_DIM) / 256,      256, 0, stream>>>(aggA, aggB, h0, hst);
  k_scan_apply <<<(B_DIM * NC * H_DIM) / 256, 256, 0, stream>>>(aarr, barr, hst, out);
}